// Round 2
// baseline (50101.962 us; speedup 1.0000x reference)
//
#include <hip/hip_runtime.h>
#include <math.h>

// Elman RNN persistent kernel. batch=64, T=2048, in=256, hidden=512, out=256, fp32.
// 256 blocks = 4 batch-groups(16 rows) x 64 col-groups(8 h-cols, 4 y-cols).
// Weights LDS-resident; h exchanged via global ping-pong + per-step flag barrier
// (agent-scope atomics; 4 independent barrier chains, one per batch-group).
// Numerics: recurrence MUST stay fp32 (error amplification ~1e4 measured in R1).

#define BB 64
#define TT 2048
#define II 256
#define HH 512
#define OO 256
#define NBLK 256
#define OUT_OFF ((size_t)BB * TT * OO)
#define FLAGS_INTS ((TT + 1) * NBLK)

// LDS layouts (float strides). Quartered rows: 4 x 132 to spread banks.
#define LDW1H 516
#define LDW1X 260
#define LDW2  528
#define LDH   528

__global__ void rnn_init(int* __restrict__ flags) {
    int i = blockIdx.x * blockDim.x + threadIdx.x;
    if (i < FLAGS_INTS) flags[i] = 0;
}

__global__ __launch_bounds__(256) void rnn_persist(
    const float* __restrict__ x, const float* __restrict__ W1,
    const float* __restrict__ b1, const float* __restrict__ W2,
    const float* __restrict__ b2, float* __restrict__ out,
    int* __restrict__ flags, float* __restrict__ hbuf)
{
    __shared__ float w1h_s[8 * LDW1H];
    __shared__ float w1x_s[8 * LDW1X];
    __shared__ float w2_s[4 * LDW2];
    __shared__ float h_s[16 * LDH];

    const int tid = threadIdx.x;
    const int blk = blockIdx.x;
    const int bi  = blk >> 6;        // 0..3  batch group (16 rows)
    const int cj  = blk & 63;        // 0..63 col group
    const int R0  = bi << 4;
    const int C0  = cj << 3;         // 8 h-cols
    const int O0  = cj << 2;         // 4 y-cols

    const int c = tid & 7;           // h-col within group
    const int s = (tid >> 3) & 1;    // K-half
    const int r = tid >> 4;          // 0..15 row
    const int oy = c & 3;            // y-col within group
    const int kq = (s << 1) | (c >> 2); // y K-quarter 0..3

    // ---- stage weights once ----
    for (int i = 0; i < 16; ++i) {
        int idx = tid + (i << 8);            // 0..4095
        int k = idx >> 3, cc = idx & 7;
        w1h_s[cc * LDW1H + k] = W1[(size_t)k * HH + C0 + cc];
    }
    for (int i = 0; i < 8; ++i) {
        int idx = tid + (i << 8);            // 0..2047
        int k = idx >> 3, cc = idx & 7;
        w1x_s[cc * LDW1X + k] = W1[(size_t)(HH + k) * HH + C0 + cc];
    }
    for (int i = 0; i < 8; ++i) {
        int idx = tid + (i << 8);            // 0..2047
        int k = idx >> 2, cc = idx & 3;
        w2_s[cc * LDW2 + (k >> 7) * 132 + (k & 127)] = W2[(size_t)k * OO + O0 + cc];
    }
    const float b1v = b1[C0 + c];
    const float b2v = b2[O0 + oy];
    __syncthreads();

    const float* xbase = x + (size_t)(R0 + r) * TT * II + (s << 7);
    float* ybase = out + (size_t)(R0 + r) * TT * OO + O0;
    const unsigned long long* hb64[2] = {
        (const unsigned long long*)hbuf,
        (const unsigned long long*)(hbuf + (size_t)BB * HH) };

    for (int t = 0; t < TT; ++t) {
        // ---- xw(t): x_t @ W1_x  (independent of h, fills wait latency) ----
        float xa0 = 0.f, xa1 = 0.f;
        {
            const float* xp = xbase + (size_t)t * II;
            const float* wp = w1x_s + c * LDW1X + (s << 7);
            #pragma unroll 8
            for (int kk = 0; kk < 128; kk += 4) {
                float4 xv = *(const float4*)(xp + kk);
                float4 wv = *(const float4*)(wp + kk);
                xa0 = fmaf(xv.x, wv.x, xa0);
                xa1 = fmaf(xv.y, wv.y, xa1);
                xa0 = fmaf(xv.z, wv.z, xa0);
                xa1 = fmaf(xv.w, wv.w, xa1);
            }
        }
        float hw0 = 0.f, hw1 = 0.f;
        if (t > 0) {
            // ---- wait for h_t from my batch-group's 64 blocks ----
            {
                const int* f = flags + (size_t)t * NBLK + (bi << 6);
                int nr;
                do {
                    int v = 1;
                    if (tid < 64)
                        v = __hip_atomic_load((int*)&f[tid], __ATOMIC_RELAXED,
                                              __HIP_MEMORY_SCOPE_AGENT);
                    nr = __syncthreads_count(v == 0);
                } while (nr != 0);
            }
            // ---- stage h_t rows R0..R0+15 (agent loads bypass stale L1/L2) ----
            const unsigned long long* hsrc = hb64[t & 1];
            #pragma unroll
            for (int i = 0; i < 16; ++i) {
                int idx = tid + (i << 8);    // 0..4095
                int rr = idx >> 8;           // 0..15
                int k2 = idx & 255;          // u64 index in row
                unsigned long long u = __hip_atomic_load(
                    (unsigned long long*)&hsrc[(size_t)(R0 + rr) * (HH / 2) + k2],
                    __ATOMIC_RELAXED, __HIP_MEMORY_SCOPE_AGENT);
                int k = k2 << 1;
                *(unsigned long long*)&h_s[rr * LDH + (k >> 7) * 132 + (k & 127)] = u;
            }
            __syncthreads();
            // ---- hw: h_t @ W1_h over K-half s (2 quarters) ----
            const float* hp = h_s + r * LDH + (s << 1) * 132;
            const float* wp = w1h_s + c * LDW1H + (s << 8);
            #pragma unroll
            for (int q = 0; q < 2; ++q) {
                const float* hq = hp + q * 132;
                const float* wq = wp + (q << 7);
                #pragma unroll 8
                for (int kk = 0; kk < 128; kk += 4) {
                    float4 hv = *(const float4*)(hq + kk);
                    float4 wv = *(const float4*)(wq + kk);
                    hw0 = fmaf(hv.x, wv.x, hw0);
                    hw1 = fmaf(hv.y, wv.y, hw1);
                    hw0 = fmaf(hv.z, wv.z, hw0);
                    hw1 = fmaf(hv.w, wv.w, hw1);
                }
            }
        }
        float tot = (hw0 + hw1) + (xa0 + xa1);
        tot += __shfl_xor(tot, 8);           // combine K-halves (s bit = tid bit 3)
        float hnew = tanhf(tot + b1v);
        if (s == 0) {
            float* hdst = hbuf + (size_t)((t + 1) & 1) * (BB * HH);
            hdst[(size_t)(R0 + r) * HH + C0 + c] = hnew;
            if (t == TT - 1)
                out[OUT_OFF + (size_t)(R0 + r) * HH + C0 + c] = hnew;
        }
        __builtin_amdgcn_fence(__ATOMIC_RELEASE, "agent");  // flush h stores (all threads)
        __syncthreads();
        if (tid == 0)
            __hip_atomic_store((int*)&flags[(size_t)(t + 1) * NBLK + blk], 1,
                               __ATOMIC_RELEASE, __HIP_MEMORY_SCOPE_AGENT);
        // ---- y_{t-1} = h_t @ W2 + b2 (h_t still in h_s; off critical path) ----
        if (t > 0) {
            float ya0 = 0.f, ya1 = 0.f;
            const float* hp = h_s + r * LDH + kq * 132;
            const float* wp = w2_s + oy * LDW2 + kq * 132;
            #pragma unroll 8
            for (int kk = 0; kk < 128; kk += 4) {
                float4 hv = *(const float4*)(hp + kk);
                float4 wv = *(const float4*)(wp + kk);
                ya0 = fmaf(hv.x, wv.x, ya0);
                ya1 = fmaf(hv.y, wv.y, ya1);
                ya0 = fmaf(hv.z, wv.z, ya0);
                ya1 = fmaf(hv.w, wv.w, ya1);
            }
            float yt = ya0 + ya1;
            yt += __shfl_xor(yt, 4);         // combine kq bit0 (tid bit 2)
            yt += __shfl_xor(yt, 8);         // combine kq bit1 (tid bit 3)
            if ((tid & 12) == 0)             // s==0 && (c>>2)==0
                ybase[(size_t)(t - 1) * OO + oy] = yt + b2v;
        }
    }
    // ---- epilogue: y_{TT-1} from h_TT ----
    {
        const int* f = flags + (size_t)TT * NBLK + (bi << 6);
        int nr;
        do {
            int v = 1;
            if (tid < 64)
                v = __hip_atomic_load((int*)&f[tid], __ATOMIC_RELAXED,
                                      __HIP_MEMORY_SCOPE_AGENT);
            nr = __syncthreads_count(v == 0);
        } while (nr != 0);
        const unsigned long long* hsrc = hb64[TT & 1];   // TT even -> buf 0
        #pragma unroll
        for (int i = 0; i < 16; ++i) {
            int idx = tid + (i << 8);
            int rr = idx >> 8;
            int k2 = idx & 255;
            unsigned long long u = __hip_atomic_load(
                (unsigned long long*)&hsrc[(size_t)(R0 + rr) * (HH / 2) + k2],
                __ATOMIC_RELAXED, __HIP_MEMORY_SCOPE_AGENT);
            int k = k2 << 1;
            *(unsigned long long*)&h_s[rr * LDH + (k >> 7) * 132 + (k & 127)] = u;
        }
        __syncthreads();
        float ya0 = 0.f, ya1 = 0.f;
        const float* hp = h_s + r * LDH + kq * 132;
        const float* wp = w2_s + oy * LDW2 + kq * 132;
        #pragma unroll 8
        for (int kk = 0; kk < 128; kk += 4) {
            float4 hv = *(const float4*)(hp + kk);
            float4 wv = *(const float4*)(wp + kk);
            ya0 = fmaf(hv.x, wv.x, ya0);
            ya1 = fmaf(hv.y, wv.y, ya1);
            ya0 = fmaf(hv.z, wv.z, ya0);
            ya1 = fmaf(hv.w, wv.w, ya1);
        }
        float yt = ya0 + ya1;
        yt += __shfl_xor(yt, 4);
        yt += __shfl_xor(yt, 8);
        if ((tid & 12) == 0)
            ybase[(size_t)(TT - 1) * OO + oy] = yt + b2v;
    }
}

extern "C" void kernel_launch(void* const* d_in, const int* in_sizes, int n_in,
                              void* d_out, int out_size, void* d_ws, size_t ws_size,
                              hipStream_t stream) {
    const float* x  = (const float*)d_in[0];
    const float* W1 = (const float*)d_in[1];
    const float* b1 = (const float*)d_in[2];
    const float* W2 = (const float*)d_in[3];
    const float* b2 = (const float*)d_in[4];
    float* out = (float*)d_out;

    int*   flags = (int*)d_ws;
    float* hbuf  = (float*)((char*)d_ws + (size_t)FLAGS_INTS * sizeof(int));

    rnn_init<<<dim3((FLAGS_INTS + 255) / 256), dim3(256), 0, stream>>>(flags);
    rnn_persist<<<dim3(NBLK), dim3(256), 0, stream>>>(x, W1, b1, W2, b2, out,
                                                      flags, hbuf);
}

// Round 3
// 17156.352 us; speedup vs baseline: 2.9203x; 2.9203x over previous
//
#include <hip/hip_runtime.h>
#include <math.h>

// Elman RNN persistent kernel. batch=64, T=2048, in=256, hidden=512, out=256, fp32.
// 256 blocks = 4 batch-groups(16 rows) x 64 col-groups(8 h-cols, 4 y-cols).
// Weights LDS-resident; h exchanged via global ping-pong + per-step flag barrier.
// R3 change vs R2: NO agent-scope release fence (gfx950 agent release fence =
// buffer_wbl2 full-L2-writeback per step = the R2 disaster). Instead, h is
// written with RELAXED AGENT atomic stores (write-through to IF$, sc1),
// ordering via s_waitcnt vmcnt(0) + __syncthreads, flag store RELAXED.
// Numerics: recurrence MUST stay fp32 (error amplification ~1e4 measured in R1).

#define BB 64
#define TT 2048
#define II 256
#define HH 512
#define OO 256
#define NBLK 256
#define OUT_OFF ((size_t)BB * TT * OO)
#define FLAGS_INTS ((TT + 1) * NBLK)

// LDS layouts (float strides). Quartered rows: 4 x 132 to spread banks.
#define LDW1H 516
#define LDW1X 260
#define LDW2  528
#define LDH   528

__global__ void rnn_init(int* __restrict__ flags) {
    int i = blockIdx.x * blockDim.x + threadIdx.x;
    if (i < FLAGS_INTS) flags[i] = 0;
}

__global__ __launch_bounds__(256) void rnn_persist(
    const float* __restrict__ x, const float* __restrict__ W1,
    const float* __restrict__ b1, const float* __restrict__ W2,
    const float* __restrict__ b2, float* __restrict__ out,
    int* __restrict__ flags, float* __restrict__ hbuf)
{
    __shared__ float w1h_s[8 * LDW1H];
    __shared__ float w1x_s[8 * LDW1X];
    __shared__ float w2_s[4 * LDW2];
    __shared__ float h_s[16 * LDH];

    const int tid = threadIdx.x;
    const int blk = blockIdx.x;
    const int bi  = blk >> 6;        // 0..3  batch group (16 rows)
    const int cj  = blk & 63;        // 0..63 col group
    const int R0  = bi << 4;
    const int C0  = cj << 3;         // 8 h-cols
    const int O0  = cj << 2;         // 4 y-cols

    const int c = tid & 7;           // h-col within group
    const int s = (tid >> 3) & 1;    // K-half
    const int r = tid >> 4;          // 0..15 row
    const int oy = c & 3;            // y-col within group
    const int kq = (s << 1) | (c >> 2); // y K-quarter 0..3

    // ---- stage weights once ----
    for (int i = 0; i < 16; ++i) {
        int idx = tid + (i << 8);            // 0..4095
        int k = idx >> 3, cc = idx & 7;
        w1h_s[cc * LDW1H + k] = W1[(size_t)k * HH + C0 + cc];
    }
    for (int i = 0; i < 8; ++i) {
        int idx = tid + (i << 8);            // 0..2047
        int k = idx >> 3, cc = idx & 7;
        w1x_s[cc * LDW1X + k] = W1[(size_t)(HH + k) * HH + C0 + cc];
    }
    for (int i = 0; i < 8; ++i) {
        int idx = tid + (i << 8);            // 0..2047
        int k = idx >> 2, cc = idx & 3;
        w2_s[cc * LDW2 + (k >> 7) * 132 + (k & 127)] = W2[(size_t)k * OO + O0 + cc];
    }
    const float b1v = b1[C0 + c];
    const float b2v = b2[O0 + oy];
    __syncthreads();

    const float* xbase = x + (size_t)(R0 + r) * TT * II + (s << 7);
    float* ybase = out + (size_t)(R0 + r) * TT * OO + O0;
    const unsigned long long* hb64[2] = {
        (const unsigned long long*)hbuf,
        (const unsigned long long*)(hbuf + (size_t)BB * HH) };

    for (int t = 0; t < TT; ++t) {
        // ---- xw(t): x_t @ W1_x  (independent of h, fills wait latency) ----
        float xa0 = 0.f, xa1 = 0.f;
        {
            const float* xp = xbase + (size_t)t * II;
            const float* wp = w1x_s + c * LDW1X + (s << 7);
            #pragma unroll 8
            for (int kk = 0; kk < 128; kk += 4) {
                float4 xv = *(const float4*)(xp + kk);
                float4 wv = *(const float4*)(wp + kk);
                xa0 = fmaf(xv.x, wv.x, xa0);
                xa1 = fmaf(xv.y, wv.y, xa1);
                xa0 = fmaf(xv.z, wv.z, xa0);
                xa1 = fmaf(xv.w, wv.w, xa1);
            }
        }
        float hw0 = 0.f, hw1 = 0.f;
        if (t > 0) {
            // ---- wait for h_t from my batch-group's 64 blocks ----
            {
                const int* f = flags + (size_t)t * NBLK + (bi << 6);
                int nr;
                do {
                    int v = 1;
                    if (tid < 64)
                        v = __hip_atomic_load((int*)&f[tid], __ATOMIC_RELAXED,
                                              __HIP_MEMORY_SCOPE_AGENT);
                    nr = __syncthreads_count(v == 0);
                } while (nr != 0);
            }
            // ---- stage h_t rows R0..R0+15 (read-through loads, IF$ coherent) ----
            const unsigned long long* hsrc = hb64[t & 1];
            #pragma unroll
            for (int i = 0; i < 16; ++i) {
                int idx = tid + (i << 8);    // 0..4095
                int rr = idx >> 8;           // 0..15
                int k2 = idx & 255;          // u64 index in row
                unsigned long long u = __hip_atomic_load(
                    (unsigned long long*)&hsrc[(size_t)(R0 + rr) * (HH / 2) + k2],
                    __ATOMIC_RELAXED, __HIP_MEMORY_SCOPE_AGENT);
                int k = k2 << 1;
                *(unsigned long long*)&h_s[rr * LDH + (k >> 7) * 132 + (k & 127)] = u;
            }
            __syncthreads();
            // ---- hw: h_t @ W1_h over K-half s (2 quarters) ----
            const float* hp = h_s + r * LDH + (s << 1) * 132;
            const float* wp = w1h_s + c * LDW1H + (s << 8);
            #pragma unroll
            for (int q = 0; q < 2; ++q) {
                const float* hq = hp + q * 132;
                const float* wq = wp + (q << 7);
                #pragma unroll 8
                for (int kk = 0; kk < 128; kk += 4) {
                    float4 hv = *(const float4*)(hq + kk);
                    float4 wv = *(const float4*)(wq + kk);
                    hw0 = fmaf(hv.x, wv.x, hw0);
                    hw1 = fmaf(hv.y, wv.y, hw1);
                    hw0 = fmaf(hv.z, wv.z, hw0);
                    hw1 = fmaf(hv.w, wv.w, hw1);
                }
            }
        }
        float tot = (hw0 + hw1) + (xa0 + xa1);
        tot += __shfl_xor(tot, 8);           // combine K-halves (s bit = tid bit 3)
        float hnew = tanhf(tot + b1v);
        if (s == 0) {
            // write-through (sc1) store: coherent at IF$, no fence needed
            float* hdst = hbuf + (size_t)((t + 1) & 1) * (BB * HH);
            __hip_atomic_store(&hdst[(size_t)(R0 + r) * HH + C0 + c], hnew,
                               __ATOMIC_RELAXED, __HIP_MEMORY_SCOPE_AGENT);
            if (t == TT - 1)
                out[OUT_OFF + (size_t)(R0 + r) * HH + C0 + c] = hnew;
        }
        // drain stores to the coherence point, then all waves rendezvous
        asm volatile("s_waitcnt vmcnt(0)" ::: "memory");
        __syncthreads();
        if (tid == 0)
            __hip_atomic_store((int*)&flags[(size_t)(t + 1) * NBLK + blk], 1,
                               __ATOMIC_RELAXED, __HIP_MEMORY_SCOPE_AGENT);
        // ---- y_{t-1} = h_t @ W2 + b2 (h_t still in h_s; off critical path) ----
        if (t > 0) {
            float ya0 = 0.f, ya1 = 0.f;
            const float* hp = h_s + r * LDH + kq * 132;
            const float* wp = w2_s + oy * LDW2 + kq * 132;
            #pragma unroll 8
            for (int kk = 0; kk < 128; kk += 4) {
                float4 hv = *(const float4*)(hp + kk);
                float4 wv = *(const float4*)(wp + kk);
                ya0 = fmaf(hv.x, wv.x, ya0);
                ya1 = fmaf(hv.y, wv.y, ya1);
                ya0 = fmaf(hv.z, wv.z, ya0);
                ya1 = fmaf(hv.w, wv.w, ya1);
            }
            float yt = ya0 + ya1;
            yt += __shfl_xor(yt, 4);         // combine kq bit0 (tid bit 2)
            yt += __shfl_xor(yt, 8);         // combine kq bit1 (tid bit 3)
            if ((tid & 12) == 0)             // s==0 && (c>>2)==0
                ybase[(size_t)(t - 1) * OO + oy] = yt + b2v;
        }
    }
    // ---- epilogue: y_{TT-1} from h_TT ----
    {
        const int* f = flags + (size_t)TT * NBLK + (bi << 6);
        int nr;
        do {
            int v = 1;
            if (tid < 64)
                v = __hip_atomic_load((int*)&f[tid], __ATOMIC_RELAXED,
                                      __HIP_MEMORY_SCOPE_AGENT);
            nr = __syncthreads_count(v == 0);
        } while (nr != 0);
        const unsigned long long* hsrc = hb64[TT & 1];   // TT even -> buf 0
        #pragma unroll
        for (int i = 0; i < 16; ++i) {
            int idx = tid + (i << 8);
            int rr = idx >> 8;
            int k2 = idx & 255;
            unsigned long long u = __hip_atomic_load(
                (unsigned long long*)&hsrc[(size_t)(R0 + rr) * (HH / 2) + k2],
                __ATOMIC_RELAXED, __HIP_MEMORY_SCOPE_AGENT);
            int k = k2 << 1;
            *(unsigned long long*)&h_s[rr * LDH + (k >> 7) * 132 + (k & 127)] = u;
        }
        __syncthreads();
        float ya0 = 0.f, ya1 = 0.f;
        const float* hp = h_s + r * LDH + kq * 132;
        const float* wp = w2_s + oy * LDW2 + kq * 132;
        #pragma unroll 8
        for (int kk = 0; kk < 128; kk += 4) {
            float4 hv = *(const float4*)(hp + kk);
            float4 wv = *(const float4*)(wp + kk);
            ya0 = fmaf(hv.x, wv.x, ya0);
            ya1 = fmaf(hv.y, wv.y, ya1);
            ya0 = fmaf(hv.z, wv.z, ya0);
            ya1 = fmaf(hv.w, wv.w, ya1);
        }
        float yt = ya0 + ya1;
        yt += __shfl_xor(yt, 4);
        yt += __shfl_xor(yt, 8);
        if ((tid & 12) == 0)
            ybase[(size_t)(TT - 1) * OO + oy] = yt + b2v;
    }
}

extern "C" void kernel_launch(void* const* d_in, const int* in_sizes, int n_in,
                              void* d_out, int out_size, void* d_ws, size_t ws_size,
                              hipStream_t stream) {
    const float* x  = (const float*)d_in[0];
    const float* W1 = (const float*)d_in[1];
    const float* b1 = (const float*)d_in[2];
    const float* W2 = (const float*)d_in[3];
    const float* b2 = (const float*)d_in[4];
    float* out = (float*)d_out;

    int*   flags = (int*)d_ws;
    float* hbuf  = (float*)((char*)d_ws + (size_t)FLAGS_INTS * sizeof(int));

    rnn_init<<<dim3((FLAGS_INTS + 255) / 256), dim3(256), 0, stream>>>(flags);
    rnn_persist<<<dim3(NBLK), dim3(256), 0, stream>>>(x, W1, b1, W2, b2, out,
                                                      flags, hbuf);
}

// Round 5
// 11059.813 us; speedup vs baseline: 4.5301x; 1.5512x over previous
//
#include <hip/hip_runtime.h>
#include <math.h>

// Elman RNN persistent kernel, R5: weights-in-registers (R4 + staging fix).
// batch=64, T=2048, in=256, hidden=512, out=256, fp32.
// 256 blocks = 4 batch-groups(16 rows) x 64 col-groups(8 h-cols, 4 y-cols).
// Per thread (r2=tid>>5 rows {r2,r2+8}, g=tid&31 k-slice {128j+4g+i}):
//   w1r[6][4][8] = W1 slice (768-K incl. x-part)  -> 192 VGPRs
//   w2r[4][4][4] = W2 slice (512-K)               ->  64 VGPRs
// LDS: v[16][776] = [h_t | x_t] activations + 16KB reduce scratch.
// R5 FIX vs R4: h staging/zero loops covered only rows 0..7 (2048 of 4096
// u64) -> rows 8..15 ran on garbage. Now 16 rows via 2 batches of 8.
// Sync protocol unchanged from R3 (relaxed-agent write-through, no fences).
// Numerics: recurrence MUST stay fp32 (error amplification ~1e4, R1).

#define BB 64
#define TT 2048
#define II 256
#define HH 512
#define OO 256
#define NBLK 256
#define OUT_OFF ((size_t)BB * TT * OO)
#define FLAGS_INTS ((TT + 1) * NBLK)
#define LDV 776            // v row stride (768 + 8 pad)

typedef unsigned long long ull;
#define F4C(v,i) ((i)==0?(v).x:((i)==1?(v).y:((i)==2?(v).z:(v).w)))

__global__ void rnn_init(int* __restrict__ flags) {
    int i = blockIdx.x * blockDim.x + threadIdx.x;
    if (i < FLAGS_INTS) flags[i] = 0;
}

__global__ __launch_bounds__(256, 1) void rnn_persist(
    const float* __restrict__ x, const float* __restrict__ W1,
    const float* __restrict__ b1, const float* __restrict__ W2,
    const float* __restrict__ b2, float* __restrict__ out,
    int* __restrict__ flags, float* __restrict__ hbuf)
{
    __shared__ float v_s[16 * LDV];      // [row][768]: h | x
    __shared__ float sc_s[16 * 8 * 32];  // reduce scratch (h: 4096, y aliases low half)

    const int tid = threadIdx.x;
    const int blk = blockIdx.x;
    const int bi  = blk >> 6;            // batch group (16 rows)
    const int cj  = blk & 63;            // col group
    const int R0  = bi << 4;
    const int C0  = cj << 3;             // 8 h-cols
    const int O0  = cj << 2;             // 4 y-cols

    const int g  = tid & 31;             // k-slice
    const int r2 = tid >> 5;             // rows r2, r2+8
    const int orow = tid >> 3, oc = tid & 7;   // h-output ids (tid<128)
    const int yrow = tid >> 2, yo = tid & 3;   // y-output ids (tid<64)

    // ---- weights into registers (one-time) ----
    float w1r[6][4][8];
    #pragma unroll
    for (int j = 0; j < 6; ++j)
        #pragma unroll
        for (int i = 0; i < 4; ++i) {
            const float* wp = W1 + (size_t)(j * 128 + (g << 2) + i) * HH + C0;
            float4 a = *(const float4*)wp;
            float4 b = *(const float4*)(wp + 4);
            w1r[j][i][0] = a.x; w1r[j][i][1] = a.y; w1r[j][i][2] = a.z; w1r[j][i][3] = a.w;
            w1r[j][i][4] = b.x; w1r[j][i][5] = b.y; w1r[j][i][6] = b.z; w1r[j][i][7] = b.w;
        }
    float w2r[4][4][4];
    #pragma unroll
    for (int j = 0; j < 4; ++j)
        #pragma unroll
        for (int i = 0; i < 4; ++i) {
            float4 a = *(const float4*)(W2 + (size_t)(j * 128 + (g << 2) + i) * OO + O0);
            w2r[j][i][0] = a.x; w2r[j][i][1] = a.y; w2r[j][i][2] = a.z; w2r[j][i][3] = a.w;
        }
    const float b1v = (tid < 128) ? b1[C0 + oc] : 0.f;
    const float b2v = (tid < 64)  ? b2[O0 + yo] : 0.f;

    const ull* hb64[2] = { (const ull*)hbuf, (const ull*)(hbuf + (size_t)BB * HH) };

    // ---- t=0: v.h = 0 (ALL 16 rows = 4096 u64), stage x(0) ----
    #pragma unroll
    for (int m = 0; m < 16; ++m) {
        int idx = (m << 8) + tid;        // 0..4095 u64
        *(ull*)&v_s[(idx >> 8) * LDV + ((idx & 255) << 1)] = 0ull;
    }
    #pragma unroll
    for (int m = 0; m < 4; ++m) {
        int idx = (m << 8) + tid;        // 0..1023 float4
        int row = idx >> 6, k4 = idx & 63;
        float4 xv = *(const float4*)&x[((size_t)(R0 + row) * TT + 0) * II + (k4 << 2)];
        *(float4*)&v_s[row * LDV + 512 + (k4 << 2)] = xv;
    }
    __syncthreads();

    for (int t = 0; t < TT; ++t) {
        if (t > 0) {
            // ---- wait for my batch-group's 64 h-producer flags ----
            if (tid < 64) {
                const int* f = flags + (size_t)t * NBLK + (bi << 6) + tid;
                while (__hip_atomic_load(f, __ATOMIC_RELAXED,
                                         __HIP_MEMORY_SCOPE_AGENT) == 0) {}
            }
            __syncthreads();   // also protects v.h from prev-iter y reads
            // ---- stage h_t: 16 rows = 4096 u64, 2 batches of 8 ----
            const ull* hsrc = hb64[t & 1];
            #pragma unroll
            for (int half = 0; half < 2; ++half) {
                ull tmp[8];
                #pragma unroll
                for (int m = 0; m < 8; ++m) {
                    int idx = (((half << 3) + m) << 8) + tid;   // 0..4095
                    tmp[m] = __hip_atomic_load(
                        (ull*)&hsrc[(size_t)(R0 + (idx >> 8)) * (HH / 2) + (idx & 255)],
                        __ATOMIC_RELAXED, __HIP_MEMORY_SCOPE_AGENT);
                }
                #pragma unroll
                for (int m = 0; m < 8; ++m) {
                    int idx = (((half << 3) + m) << 8) + tid;
                    *(ull*)&v_s[(idx >> 8) * LDV + ((idx & 255) << 1)] = tmp[m];
                }
            }
            __syncthreads();
        }

        // ---- A-GEMM: z[row][c] = sum_k v[row][k] * W1[k][c], K=768 ----
        float pa[2][8];
        #pragma unroll
        for (int rr = 0; rr < 2; ++rr)
            #pragma unroll
            for (int c = 0; c < 8; ++c) pa[rr][c] = 0.f;
        #pragma unroll
        for (int rr = 0; rr < 2; ++rr) {
            const int row = r2 + (rr << 3);
            #pragma unroll
            for (int j = 0; j < 6; ++j) {
                float4 vv = *(const float4*)&v_s[row * LDV + j * 128 + (g << 2)];
                #pragma unroll
                for (int i = 0; i < 4; ++i) {
                    const float vi = F4C(vv, i);
                    #pragma unroll
                    for (int c = 0; c < 8; ++c)
                        pa[rr][c] = fmaf(vi, w1r[j][i][c], pa[rr][c]);
                }
            }
        }
        // ---- k-reduce via swizzled scratch ----
        #pragma unroll
        for (int rr = 0; rr < 2; ++rr)
            #pragma unroll
            for (int c = 0; c < 8; ++c)
                sc_s[(((r2 + (rr << 3)) << 3) + c) * 32 + (g ^ (c << 2))] = pa[rr][c];
        __syncthreads();
        if (tid < 128) {
            float s = 0.f;
            #pragma unroll
            for (int j = 0; j < 8; ++j) {
                float4 q = *(const float4*)&sc_s[(tid << 5) + ((j << 2) ^ (oc << 2))];
                s += (q.x + q.y) + (q.z + q.w);
            }
            float hnew = tanhf(s + b1v);
            float* hdst = hbuf + (size_t)((t + 1) & 1) * (BB * HH);
            __hip_atomic_store(&hdst[(size_t)(R0 + orow) * HH + C0 + oc], hnew,
                               __ATOMIC_RELAXED, __HIP_MEMORY_SCOPE_AGENT);
            if (t == TT - 1)
                out[OUT_OFF + (size_t)(R0 + orow) * HH + C0 + oc] = hnew;
        }
        asm volatile("s_waitcnt vmcnt(0)" ::: "memory");
        __syncthreads();
        if (tid == 0)
            __hip_atomic_store((int*)&flags[(size_t)(t + 1) * NBLK + blk], 1,
                               __ATOMIC_RELAXED, __HIP_MEMORY_SCOPE_AGENT);

        // ---- prefetch x(t+1) into v.x (A-reads done; disjoint from v.h) ----
        if (t + 1 < TT) {
            #pragma unroll
            for (int m = 0; m < 4; ++m) {
                int idx = (m << 8) + tid;
                int row = idx >> 6, k4 = idx & 63;
                float4 xv = *(const float4*)&x[((size_t)(R0 + row) * TT + (t + 1)) * II + (k4 << 2)];
                *(float4*)&v_s[row * LDV + 512 + (k4 << 2)] = xv;
            }
        }

        // ---- y(t-1) = h_t @ W2 + b2 (v.h still valid; off critical path) ----
        if (t > 0) {
            float py[2][4];
            #pragma unroll
            for (int rr = 0; rr < 2; ++rr)
                #pragma unroll
                for (int o = 0; o < 4; ++o) py[rr][o] = 0.f;
            #pragma unroll
            for (int rr = 0; rr < 2; ++rr) {
                const int row = r2 + (rr << 3);
                #pragma unroll
                for (int j = 0; j < 4; ++j) {
                    float4 vv = *(const float4*)&v_s[row * LDV + j * 128 + (g << 2)];
                    #pragma unroll
                    for (int i = 0; i < 4; ++i) {
                        const float vi = F4C(vv, i);
                        #pragma unroll
                        for (int o = 0; o < 4; ++o)
                            py[rr][o] = fmaf(vi, w2r[j][i][o], py[rr][o]);
                    }
                }
            }
            #pragma unroll
            for (int rr = 0; rr < 2; ++rr)
                #pragma unroll
                for (int o = 0; o < 4; ++o)
                    sc_s[(((r2 + (rr << 3)) << 2) + o) * 32 + (g ^ (o << 2))] = py[rr][o];
            __syncthreads();
            if (tid < 64) {
                float s = 0.f;
                #pragma unroll
                for (int j = 0; j < 8; ++j) {
                    float4 q = *(const float4*)&sc_s[(tid << 5) + ((j << 2) ^ (yo << 2))];
                    s += (q.x + q.y) + (q.z + q.w);
                }
                out[((size_t)(R0 + yrow) * TT + (t - 1)) * OO + O0 + yo] = s + b2v;
            }
        }
    }

    // ---- epilogue: y(TT-1) from h_TT ----
    if (tid < 64) {
        const int* f = flags + (size_t)TT * NBLK + (bi << 6) + tid;
        while (__hip_atomic_load(f, __ATOMIC_RELAXED,
                                 __HIP_MEMORY_SCOPE_AGENT) == 0) {}
    }
    __syncthreads();
    {
        const ull* hsrc = hb64[TT & 1];   // buf 0
        #pragma unroll
        for (int half = 0; half < 2; ++half) {
            ull tmp[8];
            #pragma unroll
            for (int m = 0; m < 8; ++m) {
                int idx = (((half << 3) + m) << 8) + tid;
                tmp[m] = __hip_atomic_load(
                    (ull*)&hsrc[(size_t)(R0 + (idx >> 8)) * (HH / 2) + (idx & 255)],
                    __ATOMIC_RELAXED, __HIP_MEMORY_SCOPE_AGENT);
            }
            #pragma unroll
            for (int m = 0; m < 8; ++m) {
                int idx = (((half << 3) + m) << 8) + tid;
                *(ull*)&v_s[(idx >> 8) * LDV + ((idx & 255) << 1)] = tmp[m];
            }
        }
        __syncthreads();
        float py[2][4];
        #pragma unroll
        for (int rr = 0; rr < 2; ++rr)
            #pragma unroll
            for (int o = 0; o < 4; ++o) py[rr][o] = 0.f;
        #pragma unroll
        for (int rr = 0; rr < 2; ++rr) {
            const int row = r2 + (rr << 3);
            #pragma unroll
            for (int j = 0; j < 4; ++j) {
                float4 vv = *(const float4*)&v_s[row * LDV + j * 128 + (g << 2)];
                #pragma unroll
                for (int i = 0; i < 4; ++i) {
                    const float vi = F4C(vv, i);
                    #pragma unroll
                    for (int o = 0; o < 4; ++o)
                        py[rr][o] = fmaf(vi, w2r[j][i][o], py[rr][o]);
                }
            }
        }
        #pragma unroll
        for (int rr = 0; rr < 2; ++rr)
            #pragma unroll
            for (int o = 0; o < 4; ++o)
                sc_s[(((r2 + (rr << 3)) << 2) + o) * 32 + (g ^ (o << 2))] = py[rr][o];
        __syncthreads();
        if (tid < 64) {
            float s = 0.f;
            #pragma unroll
            for (int j = 0; j < 8; ++j) {
                float4 q = *(const float4*)&sc_s[(tid << 5) + ((j << 2) ^ (yo << 2))];
                s += (q.x + q.y) + (q.z + q.w);
            }
            out[((size_t)(R0 + yrow) * TT + (TT - 1)) * OO + O0 + yo] = s + b2v;
        }
    }
}

extern "C" void kernel_launch(void* const* d_in, const int* in_sizes, int n_in,
                              void* d_out, int out_size, void* d_ws, size_t ws_size,
                              hipStream_t stream) {
    const float* x  = (const float*)d_in[0];
    const float* W1 = (const float*)d_in[1];
    const float* b1 = (const float*)d_in[2];
    const float* W2 = (const float*)d_in[3];
    const float* b2 = (const float*)d_in[4];
    float* out = (float*)d_out;

    int*   flags = (int*)d_ws;
    float* hbuf  = (float*)((char*)d_ws + (size_t)FLAGS_INTS * sizeof(int));

    rnn_init<<<dim3((FLAGS_INTS + 255) / 256), dim3(256), 0, stream>>>(flags);
    rnn_persist<<<dim3(NBLK), dim3(256), 0, stream>>>(x, W1, b1, W2, b2, out,
                                                      flags, hbuf);
}